// Round 1
// baseline (141.019 us; speedup 1.0000x reference)
//
#include <hip/hip_runtime.h>

// VolumeRenderer: 65536 rays x <=192 DDA steps through a 128^3x4 f32 grid.
// One thread per ray (1024 waves total -> ~1 wave/SIMD, no TLP), so the
// critical trick is: delta_t is purely geometric (independent of loaded
// rgba), letting us precompute 8 addresses per chunk and keep 8 gathers in
// flight (ILP latency hiding instead of TLP).
//
// Trajectory math uses __f*_rn (no fp-contraction) to track the numpy
// reference's floor/clip boundary decisions; shading uses fast exp/rcp.

constexpr int   R_DIM    = 128;
constexpr int   N_STEPS  = 192;
constexpr float STEP_SZ  = 0.001f;
constexpr float CUBE_SZ  = 1.0f / 128.0f;
constexpr int   PIPE     = 8;   // loads in flight per chunk; 192 % 8 == 0

__device__ __forceinline__ float sigmoid_fast(float x) {
    // 1 / (1 + e^-x); rcp is v_rcp_f32 (~1 ulp), fine vs 2e-2 threshold.
    return __builtin_amdgcn_rcpf(1.0f + __expf(-x));
}

__device__ __forceinline__ int clamp_idx(float v) {
    int i = (int)floorf(v);
    i = i < 0 ? 0 : i;
    i = i > (R_DIM - 1) ? (R_DIM - 1) : i;
    return i;
}

__global__ __launch_bounds__(256) void volrend_kernel(
    const float* __restrict__ grid,     // (128,128,128,4)
    const float* __restrict__ origins,  // (B,3)
    const float* __restrict__ dirs,     // (B,3)
    float* __restrict__ out,            // (B,3)
    int B)
{
    int i = blockIdx.x * blockDim.x + threadIdx.x;
    if (i >= B) return;

    float ox = origins[3 * i + 0];
    float oy = origins[3 * i + 1];
    float oz = origins[3 * i + 2];
    float dx = dirs[3 * i + 0];
    float dy = dirs[3 * i + 1];
    float dz = dirs[3 * i + 2];

    // dirs /= ||dirs||  (f32, no contraction: match np op order)
    float n2 = __fadd_rn(__fadd_rn(__fmul_rn(dx, dx), __fmul_rn(dy, dy)),
                         __fmul_rn(dz, dz));
    float nrm = sqrtf(n2);          // IEEE sqrt
    dx = dx / nrm;                  // IEEE div
    dy = dy / nrm;
    dz = dz / nrm;

    float ix = 1.0f / __fadd_rn(dx, 1e-9f);
    float iy = 1.0f / __fadd_rn(dy, 1e-9f);
    float iz = 1.0f / __fadd_rn(dz, 1e-9f);

    // _dda_unit(origins, invdirs)
    float tmin, tmax;
    {
        float t1x = __fmul_rn(-ox, ix), t2x = __fadd_rn(t1x, ix);
        float t1y = __fmul_rn(-oy, iy), t2y = __fadd_rn(t1y, iy);
        float t1z = __fmul_rn(-oz, iz), t2z = __fadd_rn(t1z, iz);
        float lox = fminf(t1x, t2x), hix = fmaxf(t1x, t2x);
        float loy = fminf(t1y, t2y), hiy = fmaxf(t1y, t2y);
        float loz = fminf(t1z, t2z), hiz = fmaxf(t1z, t2z);
        tmin = fmaxf(fmaxf(fmaxf(lox, loy), loz), 0.0f);
        tmax = fminf(fminf(fminf(hix, hiy), hiz), 1e9f);
    }

    const float4* __restrict__ g4 = (const float4*)grid;

    float t = tmin;
    float light = 1.0f;
    float ar = 0.0f, ag = 0.0f, ab = 0.0f;

    for (int chunk = 0; chunk < N_STEPS / PIPE; ++chunk) {
        if (t >= tmax) break;   // per-lane exit; wave runs until all lanes done

        float4 val[PIPE];
        float  del[PIPE];
        float  tl = t;

        // ---- generate: addresses + deltas (no dependence on loaded data) --
        #pragma unroll
        for (int p = 0; p < PIPE; ++p) {
            // pos = o + t*d; px = pos*R  (np order, no contraction)
            float px = __fmul_rn(__fadd_rn(ox, __fmul_rn(tl, dx)), (float)R_DIM);
            float py = __fmul_rn(__fadd_rn(oy, __fmul_rn(tl, dy)), (float)R_DIM);
            float pz = __fmul_rn(__fadd_rn(oz, __fmul_rn(tl, dz)), (float)R_DIM);
            int i0 = clamp_idx(px);
            int i1 = clamp_idx(py);
            int i2 = clamp_idx(pz);

            // always-safe load (indices clamped); issues early, consumed later
            val[p] = g4[(i0 * R_DIM + i1) * R_DIM + i2];

            float fx = __fsub_rn(px, (float)i0);
            float fy = __fsub_rn(py, (float)i1);
            float fz = __fsub_rn(pz, (float)i2);

            float t1x = __fmul_rn(-fx, ix), t2x = __fadd_rn(t1x, ix);
            float t1y = __fmul_rn(-fy, iy), t2y = __fadd_rn(t1y, iy);
            float t1z = __fmul_rn(-fz, iz), t2z = __fadd_rn(t1z, iz);
            float lox = fminf(t1x, t2x), hix = fmaxf(t1x, t2x);
            float loy = fminf(t1y, t2y), hiy = fmaxf(t1y, t2y);
            float loz = fminf(t1z, t2z), hiz = fmaxf(t1z, t2z);
            float smin = fmaxf(fmaxf(fmaxf(lox, loy), loz), 0.0f);
            float smax = fminf(fminf(fminf(hix, hiy), hiz), 1e9f);

            float d = __fadd_rn(__fmul_rn(__fsub_rn(smax, smin), CUBE_SZ), STEP_SZ);
            // inactive step -> d = 0 -> att = exp(0) = 1 -> exact no-op
            d = (tl < tmax) ? d : 0.0f;
            del[p] = d;
            tl = __fadd_rn(tl, d);
        }

        // ---- consume: shading (fast math; does not feed trajectory) ------
        #pragma unroll
        for (int p = 0; p < PIPE; ++p) {
            float sigma = fmaxf(val[p].w, 0.0f);
            float att = __expf(-del[p] * sigma);
            float w = light * (1.0f - att);
            ar = fmaf(w, sigmoid_fast(val[p].x), ar);
            ag = fmaf(w, sigmoid_fast(val[p].y), ag);
            ab = fmaf(w, sigmoid_fast(val[p].z), ab);
            light *= att;
        }

        t = tl;
    }

    out[3 * i + 0] = ar + light;
    out[3 * i + 1] = ag + light;
    out[3 * i + 2] = ab + light;
}

extern "C" void kernel_launch(void* const* d_in, const int* in_sizes, int n_in,
                              void* d_out, int out_size, void* d_ws, size_t ws_size,
                              hipStream_t stream) {
    const float* grid    = (const float*)d_in[0];
    const float* origins = (const float*)d_in[1];
    const float* dirs    = (const float*)d_in[2];
    // d_in[3] (viewdirs) unused by the reference.
    float* out = (float*)d_out;

    int B = in_sizes[1] / 3;
    dim3 block(256);
    dim3 grid_dim((B + 255) / 256);
    volrend_kernel<<<grid_dim, block, 0, stream>>>(grid, origins, dirs, out, B);
}